// Round 16
// baseline (150.821 us; speedup 1.0000x reference)
//
#include <hip/hip_runtime.h>
#include <stdint.h>

#define NN 100000
#define EE 600000
#define DD 128

typedef _Float16 half8 __attribute__((ext_vector_type(8)));
typedef _Float16 h2 __attribute__((ext_vector_type(2)));
typedef float f32x4 __attribute__((ext_vector_type(4)));

static __device__ __forceinline__ uint32_t pack2(float a, float b) {
    h2 h; h.x = (_Float16)a; h.y = (_Float16)b;
    return __builtin_bit_cast(uint32_t, h);
}
static __device__ __forceinline__ h2 cvt22(float2 f) {
    h2 r; r.x = (_Float16)f.x; r.y = (_Float16)f.y; return r;
}
static __device__ __forceinline__ h2 bc_lo(h2 v) { h2 r; r.x = v.x; r.y = v.x; return r; }
static __device__ __forceinline__ h2 bc_hi(h2 v) { h2 r; r.x = v.y; r.y = v.y; return r; }

// Edge message, emb-first so the 6-op chain (dependent only on the rec load)
// overlaps the x-gather; xv joins at the end.
static __device__ __forceinline__ uint32_t edge_msg2(uint32_t rY, uint32_t rZ, uint32_t rW,
                                                     uint32_t xv, uint32_t bb,
                                                     uint32_t w0, uint32_t w1, uint32_t w2,
                                                     uint32_t w3, uint32_t w4, uint32_t w5)
{
    uint32_t m;
    asm("v_pk_fma_f16 %0, %1, %2, %3 op_sel:[0,0,0] op_sel_hi:[0,1,1]"
        : "=v"(m) : "v"(rY), "v"(w0), "v"(bb));
    asm("v_pk_fma_f16 %0, %1, %2, %0 op_sel:[1,0,0] op_sel_hi:[1,1,1]" : "+v"(m) : "v"(rY), "v"(w1));
    asm("v_pk_fma_f16 %0, %1, %2, %0 op_sel:[0,0,0] op_sel_hi:[0,1,1]" : "+v"(m) : "v"(rZ), "v"(w2));
    asm("v_pk_fma_f16 %0, %1, %2, %0 op_sel:[1,0,0] op_sel_hi:[1,1,1]" : "+v"(m) : "v"(rZ), "v"(w3));
    asm("v_pk_fma_f16 %0, %1, %2, %0 op_sel:[0,0,0] op_sel_hi:[0,1,1]" : "+v"(m) : "v"(rW), "v"(w4));
    asm("v_pk_fma_f16 %0, %1, %2, %0 op_sel:[1,0,0] op_sel_hi:[1,1,1]" : "+v"(m) : "v"(rW), "v"(w5));
    asm("v_pk_add_f16 %0, %0, %1" : "+v"(m) : "v"(xv));
    asm("v_pk_max_f16 %0, %0, 0" : "+v"(m));
    return m;
}

// ---------------------------------------------------------------------------
// Setup: [0..NB_HIST) dst histogram; [..+128) W1/W2 -> f16 MFMA B-frags.
// counts pre-zeroed via memsetAsync. (x->f16 conv pass removed — agg gathers
// f32 x directly; R9 vs R11 showed gather width is not the agg limiter, and
// the conv pass cost 77 MB of HBM traffic per call.)
// ---------------------------------------------------------------------------
#define NB_HIST ((EE + 255) / 256)
__global__ __launch_bounds__(256)
void setup2(const int* __restrict__ ei,
            const float* __restrict__ W1, const float* __restrict__ W2,
            int* __restrict__ counts,
            _Float16* __restrict__ w1h, _Float16* __restrict__ w2h)
{
    const int b = blockIdx.x, tid = threadIdx.x;
    if (b < NB_HIST) {
        int e = b * 256 + tid;
        if (e < EE) atomicAdd(&counts[ei[EE + e]], 1);
    } else {
        int t = (b - NB_HIST) * 256 + tid;
        if (t < 2 * DD * DD) {
            int which = t >> 14;
            int idx = t & (DD * DD - 1);
            int k = idx >> 7, d = idx & 127;
            float wv = (which ? W2 : W1)[k * DD + d];
            int kt = k >> 5, kr = k & 31;
            int grp = kr >> 3, j = kr & 7;
            int nt = d >> 4, cc = d & 15;
            int off = ((kt * 8 + nt) * 64 + grp * 16 + cc) * 8 + j;
            (which ? w2h : w1h)[off] = (_Float16)wv;
        }
    }
}

// ---------------------------------------------------------------------------
// Scan step 1: per-block exclusive scan over 1024 counts (256 thr x int4).
// start[] stays block-local; consumers add boff[n>>10].
// ---------------------------------------------------------------------------
__global__ __launch_bounds__(256)
void scan_blocks(const int* __restrict__ counts, int* __restrict__ startv,
                 int* __restrict__ bsum)
{
    const int t = threadIdx.x;
    const int idx = blockIdx.x * 1024 + t * 4;
    int4 v = {0, 0, 0, 0};
    if (idx < NN) v = *(const int4*)(counts + idx);     // NN % 4 == 0
    int s1 = v.x + v.y, s2 = s1 + v.z, s3 = s2 + v.w;
    const int lane = t & 63;
    int q = s3;
#pragma unroll
    for (int off = 1; off < 64; off <<= 1) {
        int u = __shfl_up(q, off, 64);
        if (lane >= off) q += u;
    }
    __shared__ int wsum[4];
    if (lane == 63) wsum[t >> 6] = q;
    __syncthreads();
    const int w = t >> 6;
    int pre = 0;
    if (w > 0) pre += wsum[0];
    if (w > 1) pre += wsum[1];
    if (w > 2) pre += wsum[2];
    const int excl = (q - s3) + pre;
    if (idx < NN) {
        int4 o = {excl, excl + v.x, excl + s1, excl + s2};
        *(int4*)(startv + idx) = o;
    }
    __syncthreads();
    if (t == 0) bsum[blockIdx.x] = wsum[0] + wsum[1] + wsum[2] + wsum[3];
}

// ---------------------------------------------------------------------------
// Scan step 2: exclusive scan of block sums (1 block, 128 thr).
// ---------------------------------------------------------------------------
__global__ __launch_bounds__(128)
void scan_top(const int* __restrict__ bsum, int* __restrict__ boff)
{
    __shared__ int sm[128];
    const int t = threadIdx.x;
    const int NB = (NN + 1023) / 1024;
    int v = (t < NB) ? bsum[t] : 0;
    sm[t] = v;
    __syncthreads();
#pragma unroll
    for (int off = 1; off < 128; off <<= 1) {
        int u = (t >= off) ? sm[t - off] : 0;
        __syncthreads();
        sm[t] += u;
        __syncthreads();
    }
    boff[t] = sm[t] - v;
}

// ---------------------------------------------------------------------------
// Scatter 16B records {src*64, h2 ea01, h2 ea23, h2 ea45} into dst-sorted
// order (src pre-shifted: *64 u32s = *128 floats via *2).
// ---------------------------------------------------------------------------
__global__ __launch_bounds__(256)
void scatter_rec(const int* __restrict__ ei, const float* __restrict__ ea,
                 const int* __restrict__ start, const int* __restrict__ boff,
                 int* __restrict__ cursor, float* __restrict__ rec)
{
    int e = blockIdx.x * 256 + threadIdx.x;
    if (e >= EE) return;
    int dst = ei[EE + e];
    int src = ei[e];
    int pos = start[dst] + boff[dst >> 10] + atomicAdd(&cursor[dst], 1);
    const float2* eap = (const float2*)(ea + e * 6);
    float2 e01 = eap[0];
    float2 e23 = eap[1];
    float2 e45 = eap[2];
    float4 r;
    r.x = __int_as_float(src << 6);
    r.y = __uint_as_float(pack2(e01.x, e01.y));
    r.z = __uint_as_float(pack2(e23.x, e23.y));
    r.w = __uint_as_float(pack2(e45.x, e45.y));
    *(float4*)(rec + (size_t)pos * 4) = r;
}

// ---------------------------------------------------------------------------
// FUSED agg + node (tier A). Block = 4 waves; wave = 16 nodes = 1 MFMA tile.
// Agg: streaming 8-deep over the wave's CSR edge range; x gathered as f32
// float2/lane and cvt'd to pk-f16 in-register (no xh buffer). h0 flushed
// packed-f16 into per-wave LDS tile (XOR swizzled). Node: MFMA GEMM1 -> h1
// (overlaid on the same LDS tile) -> GEMM2 -> LN -> out. No barriers.
// launch_bounds(256,4): 128-VGPR cap — (256,8) forced VGPR=32 + spills (R13).
// ---------------------------------------------------------------------------
__global__ __launch_bounds__(256, 4)
void fused_an(const float* __restrict__ x, const float4* __restrict__ rec,
              const float* __restrict__ We, const float* __restrict__ be,
              const int* __restrict__ start, const int* __restrict__ boff,
              const float* __restrict__ epsp,
              const _Float16* __restrict__ w1h, const _Float16* __restrict__ w2h,
              const float* __restrict__ b1, const float* __restrict__ b2,
              const float* __restrict__ gamma, const float* __restrict__ beta,
              float* __restrict__ out)
{
    __shared__ _Float16 hbuf[4][16 * 128];   // 16 KiB, 4 KiB per wave
    const int wv = threadIdx.x >> 6;
    const int lane = threadIdx.x & 63;
    const int n0w = blockIdx.x * 64 + wv * 16;
    _Float16* hb = hbuf[wv];

    // ================= agg phase =================
    if (n0w < NN) {
        int n1w = n0w + 16; if (n1w > NN) n1w = NN;
        const int span = n1w - n0w;
        const int d0 = lane * 2;
        const uint32_t w0u = __builtin_bit_cast(uint32_t, cvt22(*(const float2*)(We + 0 * DD + d0)));
        const uint32_t w1u = __builtin_bit_cast(uint32_t, cvt22(*(const float2*)(We + 1 * DD + d0)));
        const uint32_t w2u = __builtin_bit_cast(uint32_t, cvt22(*(const float2*)(We + 2 * DD + d0)));
        const uint32_t w3u = __builtin_bit_cast(uint32_t, cvt22(*(const float2*)(We + 3 * DD + d0)));
        const uint32_t w4u = __builtin_bit_cast(uint32_t, cvt22(*(const float2*)(We + 4 * DD + d0)));
        const uint32_t w5u = __builtin_bit_cast(uint32_t, cvt22(*(const float2*)(We + 5 * DD + d0)));
        const uint32_t bbu = __builtin_bit_cast(uint32_t, cvt22(*(const float2*)(be + d0)));
        const float sc = 1.0f + epsp[0];

        int gs = 0;
        {
            int nidx = n0w + lane;
            if (lane <= span) gs = (nidx < NN) ? (start[nidx] + boff[nidx >> 10]) : EE;
        }
        const int ebase = __shfl(gs, 0, 64);
        const int eend  = __shfl(gs, span, 64);

        int n = n0w;
        int nstop = __shfl(gs, 1, 64);
        float2 xn = *(const float2*)(x + (size_t)n0w * DD + d0);
        float ax = 0.f, ay = 0.f;

#define FLUSH_H0()                                                               \
        {                                                                        \
            const int row = n - n0w;                                             \
            *(uint32_t*)&hb[row * 128 + (d0 ^ ((row & 7) << 4))] =               \
                pack2(fmaf(sc, xn.x, ax), fmaf(sc, xn.y, ay));                   \
        }

#define STEP(K, MK)                                                              \
        {                                                                        \
            const int ek = e + K;                                                \
            if (ek < eend) {                                                     \
                while (ek >= nstop) {                                            \
                    FLUSH_H0();                                                  \
                    ax = 0.f; ay = 0.f; ++n;                                     \
                    xn = *(const float2*)(x + (size_t)n * DD + d0);              \
                    nstop = __shfl(gs, n - n0w + 1, 64);                         \
                }                                                                \
                h2 mh = __builtin_bit_cast(h2, MK);                              \
                ax += (float)mh.x; ay += (float)mh.y;                            \
            }                                                                    \
        }

        for (int e = ebase; e < eend; e += 8) {
            const int last = eend - 1;
            int idx[8];
            float4 r[8];
            uint32_t xv[8], m[8];
#pragma unroll
            for (int k = 0; k < 8; ++k) {
                int ik = e + k;
                idx[k] = ik < eend ? ik : last;
            }
#pragma unroll
            for (int k = 0; k < 8; ++k) r[k] = rec[idx[k]];
#pragma unroll
            for (int k = 0; k < 8; ++k) {
                // rec.x = src*64 (u32s); f32 row offset = src*128 = (src*64)*2
                float2 xf = *(const float2*)(x + ((size_t)(uint32_t)__float_as_int(r[k].x)) * 2 + d0);
                xv[k] = __builtin_bit_cast(uint32_t, cvt22(xf));
            }
#pragma unroll
            for (int k = 0; k < 8; ++k)
                m[k] = edge_msg2(__float_as_uint(r[k].y), __float_as_uint(r[k].z),
                                 __float_as_uint(r[k].w), xv[k], bbu,
                                 w0u, w1u, w2u, w3u, w4u, w5u);
            STEP(0, m[0])
            STEP(1, m[1])
            STEP(2, m[2])
            STEP(3, m[3])
            STEP(4, m[4])
            STEP(5, m[5])
            STEP(6, m[6])
            STEP(7, m[7])
        }
#undef STEP

        // flush remaining (and empty/edge-less) nodes
        while (n < n1w) {
            FLUSH_H0();
            ax = 0.f; ay = 0.f; ++n;
            if (n < n1w) xn = *(const float2*)(x + (size_t)n * DD + d0);
        }
#undef FLUSH_H0
    }

    // ================= node phase =================
    const int l  = lane;
    const int lm = l & 15;
    const int lg = l >> 4;
    const int r0 = n0w;

    // A1 fragments from the wave's h0 LDS tile (XOR swizzle)
    half8 a1[4];
    {
        const int sw = (lm & 7) << 4;
        const _Float16* rowp = hb + lm * 128;
#pragma unroll
        for (int kt = 0; kt < 4; ++kt) {
            const int kb = kt * 32 + lg * 8;
            a1[kt] = *(const half8*)(rowp + (kb ^ sw));
        }
    }

    f32x4 acc[8];
#pragma unroll
    for (int nt = 0; nt < 8; ++nt) { acc[nt][0]=0.f; acc[nt][1]=0.f; acc[nt][2]=0.f; acc[nt][3]=0.f; }
#pragma unroll
    for (int kt = 0; kt < 4; ++kt) {
#pragma unroll
        for (int nt = 0; nt < 8; ++nt) {
            half8 bh = *(const half8*)(w1h + ((size_t)((kt * 8 + nt) * 64 + l)) * 8);
            acc[nt] = __builtin_amdgcn_mfma_f32_16x16x32_f16(a1[kt], bh, acc[nt], 0, 0, 0);
        }
    }

    // h1 overlaid on the same per-wave LDS tile (all a1 reads precede, in-order)
#pragma unroll
    for (int nt = 0; nt < 8; ++nt) {
        const int col = nt * 16 + lm;
        const float bias = b1[col];
#pragma unroll
        for (int q = 0; q < 4; ++q) {
            const int row = lg * 4 + q;
            float v1 = fmaxf(acc[nt][q] + bias, 0.f);
            hb[row * 128 + (col ^ ((row & 7) << 4))] = (_Float16)v1;
        }
    }

    half8 a2[4];
    {
        const int sw = (lm & 7) << 4;
        const _Float16* rowp = hb + lm * 128;
#pragma unroll
        for (int kt = 0; kt < 4; ++kt) {
            const int kb = kt * 32 + lg * 8;
            a2[kt] = *(const half8*)(rowp + (kb ^ sw));
        }
    }

    f32x4 acc2[8];
#pragma unroll
    for (int nt = 0; nt < 8; ++nt) { acc2[nt][0]=0.f; acc2[nt][1]=0.f; acc2[nt][2]=0.f; acc2[nt][3]=0.f; }
#pragma unroll
    for (int kt = 0; kt < 4; ++kt) {
#pragma unroll
        for (int nt = 0; nt < 8; ++nt) {
            half8 bh = *(const half8*)(w2h + ((size_t)((kt * 8 + nt) * 64 + l)) * 8);
            acc2[nt] = __builtin_amdgcn_mfma_f32_16x16x32_f16(a2[kt], bh, acc2[nt], 0, 0, 0);
        }
    }

    // LN stats from acc2+bias (no vv[] buffer — recompute at writeout)
    float sums[4] = {0,0,0,0}, sqs[4] = {0,0,0,0};
#pragma unroll
    for (int nt = 0; nt < 8; ++nt) {
        const float bias = b2[nt * 16 + lm];
#pragma unroll
        for (int q = 0; q < 4; ++q) {
            float v2 = acc2[nt][q] + bias;
            sums[q] += v2;
            sqs[q]  += v2 * v2;
        }
    }
#pragma unroll
    for (int m = 1; m < 16; m <<= 1) {
#pragma unroll
        for (int q = 0; q < 4; ++q) {
            sums[q] += __shfl_xor(sums[q], m, 64);
            sqs[q]  += __shfl_xor(sqs[q],  m, 64);
        }
    }

    float gam[8], bet[8], b2r[8];
#pragma unroll
    for (int nt = 0; nt < 8; ++nt) {
        gam[nt] = gamma[nt * 16 + lm];
        bet[nt] = beta[nt * 16 + lm];
        b2r[nt] = b2[nt * 16 + lm];
    }
#pragma unroll
    for (int q = 0; q < 4; ++q) {
        const int grow = r0 + lg * 4 + q;
        if (grow < NN) {
            const float mu  = sums[q] * (1.f / 128.f);
            const float var = sqs[q] * (1.f / 128.f) - mu * mu;
            const float rs  = rsqrtf(var + 1e-5f);
#pragma unroll
            for (int nt = 0; nt < 8; ++nt) {
                float v2 = acc2[nt][q] + b2r[nt];
                out[(size_t)grow * DD + nt * 16 + lm] =
                    fmaxf((v2 - mu) * rs * gam[nt] + bet[nt], 0.f);
            }
        }
    }
}

// ---------------------------------------------------------------------------
// Tier-C fallback kernels (atomic scatter path).
// ---------------------------------------------------------------------------
__global__ __launch_bounds__(256)
void prep_w(const float* __restrict__ W1, const float* __restrict__ W2,
            _Float16* __restrict__ w1h, _Float16* __restrict__ w2h)
{
    int t = blockIdx.x * 256 + threadIdx.x;
    if (t >= 2 * DD * DD) return;
    int which = t >> 14;
    int idx = t & (DD * DD - 1);
    int k = idx >> 7, d = idx & 127;
    float wv = (which ? W2 : W1)[k * DD + d];
    int kt = k >> 5, kr = k & 31;
    int grp = kr >> 3, j = kr & 7;
    int nt = d >> 4, cc = d & 15;
    int off = ((kt * 8 + nt) * 64 + grp * 16 + cc) * 8 + j;
    (which ? w2h : w1h)[off] = (_Float16)wv;
}

__global__ __launch_bounds__(256)
void edge_kernel(const float* __restrict__ x, const int* __restrict__ ei,
                 const float* __restrict__ ea, const float* __restrict__ We,
                 const float* __restrict__ be, float* agg)
{
    int tid = blockIdx.x * 256 + threadIdx.x;
    int d0 = (tid & 31) * 4;
    float4 w0 = *(const float4*)(We + 0 * DD + d0);
    float4 w1 = *(const float4*)(We + 1 * DD + d0);
    float4 w2 = *(const float4*)(We + 2 * DD + d0);
    float4 w3 = *(const float4*)(We + 3 * DD + d0);
    float4 w4 = *(const float4*)(We + 4 * DD + d0);
    float4 w5 = *(const float4*)(We + 5 * DD + d0);
    float4 bb = *(const float4*)(be + d0);
    int estride = (gridDim.x * 256) >> 5;
    for (int e = tid >> 5; e < EE; e += estride) {
        int src = ei[e];
        int dst = ei[EE + e];
        const float2* eap = (const float2*)(ea + e * 6);
        float2 e01 = eap[0];
        float2 e23 = eap[1];
        float2 e45 = eap[2];
        float4 xj = *(const float4*)(x + (size_t)src * DD + d0);
        float mx = xj.x + bb.x + e01.x*w0.x + e01.y*w1.x + e23.x*w2.x + e23.y*w3.x + e45.x*w4.x + e45.y*w5.x;
        float my = xj.y + bb.y + e01.x*w0.y + e01.y*w1.y + e23.x*w2.y + e23.y*w3.y + e45.x*w4.y + e45.y*w5.y;
        float mz = xj.z + bb.z + e01.x*w0.z + e01.y*w1.z + e23.x*w2.z + e23.y*w3.z + e45.x*w4.z + e45.y*w5.z;
        float mw = xj.w + bb.w + e01.x*w0.w + e01.y*w1.w + e23.x*w2.w + e23.y*w3.w + e45.x*w4.w + e45.y*w5.w;
        float* ap = agg + (size_t)dst * DD + d0;
        atomicAdd(ap + 0, fmaxf(mx, 0.f));
        atomicAdd(ap + 1, fmaxf(my, 0.f));
        atomicAdd(ap + 2, fmaxf(mz, 0.f));
        atomicAdd(ap + 3, fmaxf(mw, 0.f));
    }
}

__global__ __launch_bounds__(256)
void node2c(const float* __restrict__ aggp, const float* __restrict__ xp,
            const _Float16* __restrict__ w1h, const _Float16* __restrict__ w2h,
            const float* __restrict__ b1, const float* __restrict__ b2,
            const float* __restrict__ gamma, const float* __restrict__ beta,
            const float* __restrict__ epsp, float* __restrict__ out)
{
    __shared__ _Float16 h1buf[4][16 * 128];
    const int wv = threadIdx.x >> 6;
    const int l  = threadIdx.x & 63;
    const int lm = l & 15;
    const int lg = l >> 4;
    const int rbase = blockIdx.x * 128 + wv * 32;

    float gam[8], bet[8];
#pragma unroll
    for (int nt = 0; nt < 8; ++nt) {
        gam[nt] = gamma[nt * 16 + lm];
        bet[nt] = beta[nt * 16 + lm];
    }

    for (int t = 0; t < 2; ++t) {
        const int r0 = rbase + t * 16;
        int arow = r0 + lm;
        if (arow >= NN) arow = NN - 1;

        half8 a1[4];
#pragma unroll
        for (int kt = 0; kt < 4; ++kt) {
            const int kb = kt * 32 + lg * 8;
            const float4* hp = (const float4*)(aggp + (size_t)arow * DD + kb);
            float4 p0 = hp[0], p1 = hp[1];
            const float scale = 1.0f + epsp[0];
            const float4* xr = (const float4*)(xp + (size_t)arow * DD + kb);
            float4 x0 = xr[0], x1 = xr[1];
            float v[8] = { x0.x*scale+p0.x, x0.y*scale+p0.y, x0.z*scale+p0.z, x0.w*scale+p0.w,
                           x1.x*scale+p1.x, x1.y*scale+p1.y, x1.z*scale+p1.z, x1.w*scale+p1.w };
#pragma unroll
            for (int j = 0; j < 8; ++j) a1[kt][j] = (_Float16)v[j];
        }

        f32x4 acc[8];
#pragma unroll
        for (int nt = 0; nt < 8; ++nt) { acc[nt][0]=0.f; acc[nt][1]=0.f; acc[nt][2]=0.f; acc[nt][3]=0.f; }
#pragma unroll
        for (int kt = 0; kt < 4; ++kt) {
#pragma unroll
            for (int nt = 0; nt < 8; ++nt) {
                half8 bh = *(const half8*)(w1h + ((size_t)((kt * 8 + nt) * 64 + l)) * 8);
                acc[nt] = __builtin_amdgcn_mfma_f32_16x16x32_f16(a1[kt], bh, acc[nt], 0, 0, 0);
            }
        }

        _Float16* hb = h1buf[wv];
#pragma unroll
        for (int nt = 0; nt < 8; ++nt) {
            const int col = nt * 16 + lm;
            const float bias = b1[col];
#pragma unroll
            for (int q = 0; q < 4; ++q) {
                const int row = lg * 4 + q;
                float v1 = fmaxf(acc[nt][q] + bias, 0.f);
                hb[row * 128 + (col ^ ((row & 7) << 4))] = (_Float16)v1;
            }
        }

        half8 a2[4];
        {
            const int sw = (lm & 7) << 4;
            const _Float16* rowp = hb + lm * 128;
#pragma unroll
            for (int kt = 0; kt < 4; ++kt) {
                const int kb = kt * 32 + lg * 8;
                a2[kt] = *(const half8*)(rowp + (kb ^ sw));
            }
        }

        f32x4 acc2[8];
#pragma unroll
        for (int nt = 0; nt < 8; ++nt) { acc2[nt][0]=0.f; acc2[nt][1]=0.f; acc2[nt][2]=0.f; acc2[nt][3]=0.f; }
#pragma unroll
        for (int kt = 0; kt < 4; ++kt) {
#pragma unroll
            for (int nt = 0; nt < 8; ++nt) {
                half8 bh = *(const half8*)(w2h + ((size_t)((kt * 8 + nt) * 64 + l)) * 8);
                acc2[nt] = __builtin_amdgcn_mfma_f32_16x16x32_f16(a2[kt], bh, acc2[nt], 0, 0, 0);
            }
        }

        float vv[8][4];
        float sums[4] = {0,0,0,0}, sqs[4] = {0,0,0,0};
#pragma unroll
        for (int nt = 0; nt < 8; ++nt) {
            const int col = nt * 16 + lm;
            const float bias = b2[col];
#pragma unroll
            for (int q = 0; q < 4; ++q) {
                float v2 = acc2[nt][q] + bias;
                vv[nt][q] = v2;
                sums[q] += v2;
                sqs[q]  += v2 * v2;
            }
        }
#pragma unroll
        for (int m = 1; m < 16; m <<= 1) {
#pragma unroll
            for (int q = 0; q < 4; ++q) {
                sums[q] += __shfl_xor(sums[q], m, 64);
                sqs[q]  += __shfl_xor(sqs[q],  m, 64);
            }
        }
#pragma unroll
        for (int q = 0; q < 4; ++q) {
            const int grow = r0 + lg * 4 + q;
            if (grow < NN) {
                const float mu  = sums[q] * (1.f / 128.f);
                const float var = sqs[q] * (1.f / 128.f) - mu * mu;
                const float rs  = rsqrtf(var + 1e-5f);
#pragma unroll
                for (int nt = 0; nt < 8; ++nt) {
                    out[(size_t)grow * DD + nt * 16 + lm] =
                        fmaxf((vv[nt][q] - mu) * rs * gam[nt] + bet[nt], 0.f);
                }
            }
        }
    }
}

extern "C" void kernel_launch(void* const* d_in, const int* in_sizes, int n_in,
                              void* d_out, int out_size, void* d_ws, size_t ws_size,
                              hipStream_t stream) {
    (void)in_sizes; (void)n_in; (void)out_size;
    const float* x     = (const float*)d_in[0];
    const int*   ei    = (const int*)d_in[1];
    const float* ea    = (const float*)d_in[2];
    const float* We    = (const float*)d_in[4];
    const float* be    = (const float*)d_in[5];
    const float* epsp  = (const float*)d_in[6];
    const float* W1    = (const float*)d_in[7];
    const float* b1    = (const float*)d_in[8];
    const float* W2    = (const float*)d_in[9];
    const float* b2    = (const float*)d_in[10];
    const float* gamma = (const float*)d_in[11];
    const float* beta  = (const float*)d_in[12];
    float* out = (float*)d_out;

    // ---- workspace layout (16B-aligned)
    char* ws = (char*)d_ws;
    _Float16* w1h = (_Float16*)ws;
    _Float16* w2h = w1h + DD * DD;
    size_t off = 2 * (size_t)DD * DD * sizeof(_Float16);      // 65536
    int* counts = (int*)(ws + off);   off += (size_t)NN * 4;
    int* cursor = (int*)(ws + off);   off += (size_t)NN * 4;
    int* start  = (int*)(ws + off);   off += (size_t)NN * 4;
    int* bsum   = (int*)(ws + off);   off += 512;
    int* boff   = (int*)(ws + off);   off += 512;
    float* rec  = (float*)(ws + off); off += (size_t)EE * 16;
    const size_t need_rec = off;                               // ~11.3 MB

    const int node_blocks = (NN + 127) / 128;
    const int fused_blocks = (NN + 63) / 64;
    const int NBLK = (NN + 1023) / 1024;

    if (ws_size >= need_rec) {
        hipMemsetAsync(counts, 0, 2 * (size_t)NN * 4, stream);  // counts + cursor
        setup2<<<NB_HIST + 128, 256, 0, stream>>>(ei, W1, W2, counts, w1h, w2h);
        scan_blocks<<<NBLK, 256, 0, stream>>>(counts, start, bsum);
        scan_top<<<1, 128, 0, stream>>>(bsum, boff);
        scatter_rec<<<(EE + 255) / 256, 256, 0, stream>>>(ei, ea, start, boff, cursor, rec);
        fused_an<<<fused_blocks, 256, 0, stream>>>(x, (const float4*)rec, We, be,
                                                   start, boff, epsp, w1h, w2h,
                                                   b1, b2, gamma, beta, out);
    } else {
        // Tier C: atomic scatter into d_out, node computes h0 in-kernel.
        hipMemsetAsync(d_out, 0, (size_t)NN * DD * sizeof(float), stream);
        prep_w<<<(2 * DD * DD + 255) / 256, 256, 0, stream>>>(W1, W2, w1h, w2h);
        edge_kernel<<<2048, 256, 0, stream>>>(x, ei, ea, We, be, out);
        node2c<<<node_blocks, 256, 0, stream>>>(out, x, w1h, w2h, b1, b2,
                                                gamma, beta, epsp, out);
    }
}

// Round 17
// 142.477 us; speedup vs baseline: 1.0586x; 1.0586x over previous
//
#include <hip/hip_runtime.h>
#include <stdint.h>

#define NN 100000
#define EE 600000
#define DD 128

typedef _Float16 half8 __attribute__((ext_vector_type(8)));
typedef _Float16 h2 __attribute__((ext_vector_type(2)));
typedef float f32x4 __attribute__((ext_vector_type(4)));

static __device__ __forceinline__ uint32_t pack2(float a, float b) {
    h2 h; h.x = (_Float16)a; h.y = (_Float16)b;
    return __builtin_bit_cast(uint32_t, h);
}
static __device__ __forceinline__ h2 cvt22(float2 f) {
    h2 r; r.x = (_Float16)f.x; r.y = (_Float16)f.y; return r;
}
static __device__ __forceinline__ h2 bc_lo(h2 v) { h2 r; r.x = v.x; r.y = v.x; return r; }
static __device__ __forceinline__ h2 bc_hi(h2 v) { h2 r; r.x = v.y; r.y = v.y; return r; }

// Edge message, emb-first so the 6-op chain (dependent only on the rec load)
// overlaps the x-gather; xv joins at the end.
static __device__ __forceinline__ uint32_t edge_msg2(uint32_t rY, uint32_t rZ, uint32_t rW,
                                                     uint32_t xv, uint32_t bb,
                                                     uint32_t w0, uint32_t w1, uint32_t w2,
                                                     uint32_t w3, uint32_t w4, uint32_t w5)
{
    uint32_t m;
    asm("v_pk_fma_f16 %0, %1, %2, %3 op_sel:[0,0,0] op_sel_hi:[0,1,1]"
        : "=v"(m) : "v"(rY), "v"(w0), "v"(bb));
    asm("v_pk_fma_f16 %0, %1, %2, %0 op_sel:[1,0,0] op_sel_hi:[1,1,1]" : "+v"(m) : "v"(rY), "v"(w1));
    asm("v_pk_fma_f16 %0, %1, %2, %0 op_sel:[0,0,0] op_sel_hi:[0,1,1]" : "+v"(m) : "v"(rZ), "v"(w2));
    asm("v_pk_fma_f16 %0, %1, %2, %0 op_sel:[1,0,0] op_sel_hi:[1,1,1]" : "+v"(m) : "v"(rZ), "v"(w3));
    asm("v_pk_fma_f16 %0, %1, %2, %0 op_sel:[0,0,0] op_sel_hi:[0,1,1]" : "+v"(m) : "v"(rW), "v"(w4));
    asm("v_pk_fma_f16 %0, %1, %2, %0 op_sel:[1,0,0] op_sel_hi:[1,1,1]" : "+v"(m) : "v"(rW), "v"(w5));
    asm("v_pk_add_f16 %0, %0, %1" : "+v"(m) : "v"(xv));
    asm("v_pk_max_f16 %0, %0, 0" : "+v"(m));
    return m;
}

// ---------------------------------------------------------------------------
// Fused setup: [0..NB_HIST) dst histogram; [..+NB_CONV) x -> f16 (xh);
// [..+128) W1/W2 -> f16 MFMA B-frags. counts pre-zeroed via memsetAsync.
// (xh kept: R16 showed f32 gathers double HBM fetch — f16 rows stay cache-hot.)
// ---------------------------------------------------------------------------
#define NB_HIST ((EE + 255) / 256)
#define NB_CONV (NN * DD / 4 / 256)
template<bool CONV>
__global__ __launch_bounds__(256)
void setup_kernel(const int* __restrict__ ei, const float* __restrict__ x,
                  const float* __restrict__ W1, const float* __restrict__ W2,
                  int* __restrict__ counts, uint32_t* __restrict__ xh,
                  _Float16* __restrict__ w1h, _Float16* __restrict__ w2h)
{
    const int nbc = CONV ? NB_CONV : 0;
    const int b = blockIdx.x, tid = threadIdx.x;
    if (b < NB_HIST) {
        int e = b * 256 + tid;
        if (e < EE) atomicAdd(&counts[ei[EE + e]], 1);
    } else if (CONV && b < NB_HIST + nbc) {
        int i = (b - NB_HIST) * 256 + tid;               // < NN*DD/4
        float4 v = ((const float4*)x)[i];
        uint2 o; o.x = pack2(v.x, v.y); o.y = pack2(v.z, v.w);
        ((uint2*)xh)[i] = o;
    } else {
        int t = (b - NB_HIST - nbc) * 256 + tid;
        if (t < 2 * DD * DD) {
            int which = t >> 14;
            int idx = t & (DD * DD - 1);
            int k = idx >> 7, d = idx & 127;
            float wv = (which ? W2 : W1)[k * DD + d];
            int kt = k >> 5, kr = k & 31;
            int grp = kr >> 3, j = kr & 7;
            int nt = d >> 4, cc = d & 15;
            int off = ((kt * 8 + nt) * 64 + grp * 16 + cc) * 8 + j;
            (which ? w2h : w1h)[off] = (_Float16)wv;
        }
    }
}

// ---------------------------------------------------------------------------
// Scan step 1: per-block exclusive scan over 1024 counts (256 thr x int4).
// start[] stays block-local; consumers add boff[n>>10].
// ---------------------------------------------------------------------------
__global__ __launch_bounds__(256)
void scan_blocks(const int* __restrict__ counts, int* __restrict__ startv,
                 int* __restrict__ bsum)
{
    const int t = threadIdx.x;
    const int idx = blockIdx.x * 1024 + t * 4;
    int4 v = {0, 0, 0, 0};
    if (idx < NN) v = *(const int4*)(counts + idx);     // NN % 4 == 0
    int s1 = v.x + v.y, s2 = s1 + v.z, s3 = s2 + v.w;
    const int lane = t & 63;
    int q = s3;
#pragma unroll
    for (int off = 1; off < 64; off <<= 1) {
        int u = __shfl_up(q, off, 64);
        if (lane >= off) q += u;
    }
    __shared__ int wsum[4];
    if (lane == 63) wsum[t >> 6] = q;
    __syncthreads();
    const int w = t >> 6;
    int pre = 0;
    if (w > 0) pre += wsum[0];
    if (w > 1) pre += wsum[1];
    if (w > 2) pre += wsum[2];
    const int excl = (q - s3) + pre;
    if (idx < NN) {
        int4 o = {excl, excl + v.x, excl + s1, excl + s2};
        *(int4*)(startv + idx) = o;
    }
    __syncthreads();
    if (t == 0) bsum[blockIdx.x] = wsum[0] + wsum[1] + wsum[2] + wsum[3];
}

// ---------------------------------------------------------------------------
// Scan step 2: exclusive scan of block sums (1 block, 128 thr).
// ---------------------------------------------------------------------------
__global__ __launch_bounds__(128)
void scan_top(const int* __restrict__ bsum, int* __restrict__ boff)
{
    __shared__ int sm[128];
    const int t = threadIdx.x;
    const int NB = (NN + 1023) / 1024;
    int v = (t < NB) ? bsum[t] : 0;
    sm[t] = v;
    __syncthreads();
#pragma unroll
    for (int off = 1; off < 128; off <<= 1) {
        int u = (t >= off) ? sm[t - off] : 0;
        __syncthreads();
        sm[t] += u;
        __syncthreads();
    }
    boff[t] = sm[t] - v;
}

// ---------------------------------------------------------------------------
// Scatter 16B records {src*64, h2 ea01, h2 ea23, h2 ea45} into dst-sorted
// order (src pre-shifted so agg's xh gather index is a single add).
// ---------------------------------------------------------------------------
__global__ __launch_bounds__(256)
void scatter_rec(const int* __restrict__ ei, const float* __restrict__ ea,
                 const int* __restrict__ start, const int* __restrict__ boff,
                 int* __restrict__ cursor, float* __restrict__ rec)
{
    int e = blockIdx.x * 256 + threadIdx.x;
    if (e >= EE) return;
    int dst = ei[EE + e];
    int src = ei[e];
    int pos = start[dst] + boff[dst >> 10] + atomicAdd(&cursor[dst], 1);
    const float2* eap = (const float2*)(ea + e * 6);
    float2 e01 = eap[0];
    float2 e23 = eap[1];
    float2 e45 = eap[2];
    float4 r;
    r.x = __int_as_float(src << 6);
    r.y = __uint_as_float(pack2(e01.x, e01.y));
    r.z = __uint_as_float(pack2(e23.x, e23.y));
    r.w = __uint_as_float(pack2(e45.x, e45.y));
    *(float4*)(rec + (size_t)pos * 4) = r;
}

// ---------------------------------------------------------------------------
// FUSED agg + node (tier A). Block = 4 waves; wave = 16 nodes = 1 MFMA tile.
// Agg: streaming 8-deep DOUBLE-BUFFERED over the wave's CSR edge range —
// batch i+1's 16 loads (rec + xh) issue before batch i's compute, so loads
// stay in flight across the branchy flush code. h0 flushed packed-f16 into
// per-wave LDS tile (XOR swizzled). Node: MFMA GEMM1 -> h1 (overlaid on the
// same LDS tile) -> GEMM2 -> LN -> out. No barriers (LDS wave-private).
// launch_bounds(256,4): 128-VGPR cap — (256,8) forced VGPR=32 + spills (R13).
// ---------------------------------------------------------------------------
__global__ __launch_bounds__(256, 4)
void fused_an(const uint32_t* __restrict__ xh, const float4* __restrict__ rec,
              const float* __restrict__ We, const float* __restrict__ be,
              const int* __restrict__ start, const int* __restrict__ boff,
              const float* __restrict__ epsp,
              const _Float16* __restrict__ w1h, const _Float16* __restrict__ w2h,
              const float* __restrict__ b1, const float* __restrict__ b2,
              const float* __restrict__ gamma, const float* __restrict__ beta,
              float* __restrict__ out)
{
    __shared__ _Float16 hbuf[4][16 * 128];   // 16 KiB, 4 KiB per wave
    const int wv = threadIdx.x >> 6;
    const int lane = threadIdx.x & 63;
    const int n0w = blockIdx.x * 64 + wv * 16;
    _Float16* hb = hbuf[wv];

    // ================= agg phase =================
    if (n0w < NN) {
        int n1w = n0w + 16; if (n1w > NN) n1w = NN;
        const int span = n1w - n0w;
        const int d0 = lane * 2;
        const uint32_t w0u = __builtin_bit_cast(uint32_t, cvt22(*(const float2*)(We + 0 * DD + d0)));
        const uint32_t w1u = __builtin_bit_cast(uint32_t, cvt22(*(const float2*)(We + 1 * DD + d0)));
        const uint32_t w2u = __builtin_bit_cast(uint32_t, cvt22(*(const float2*)(We + 2 * DD + d0)));
        const uint32_t w3u = __builtin_bit_cast(uint32_t, cvt22(*(const float2*)(We + 3 * DD + d0)));
        const uint32_t w4u = __builtin_bit_cast(uint32_t, cvt22(*(const float2*)(We + 4 * DD + d0)));
        const uint32_t w5u = __builtin_bit_cast(uint32_t, cvt22(*(const float2*)(We + 5 * DD + d0)));
        const uint32_t bbu = __builtin_bit_cast(uint32_t, cvt22(*(const float2*)(be + d0)));
        const float sc = 1.0f + epsp[0];

        int gs = 0;
        {
            int nidx = n0w + lane;
            if (lane <= span) gs = (nidx < NN) ? (start[nidx] + boff[nidx >> 10]) : EE;
        }
        const int ebase = __shfl(gs, 0, 64);
        const int eend  = __shfl(gs, span, 64);

        int n = n0w;
        int nstop = __shfl(gs, 1, 64);
        h2 xnh = __builtin_bit_cast(h2, xh[((uint32_t)n0w << 6) + lane]);
        float ax = 0.f, ay = 0.f;

#define LOAD_BATCH(EB, RARR, XARR)                                               \
        {                                                                        \
            const int last = eend - 1;                                           \
            _Pragma("unroll")                                                    \
            for (int k = 0; k < 8; ++k) {                                        \
                int ik = (EB) + k;                                               \
                RARR[k] = rec[ik < eend ? ik : last];                            \
            }                                                                    \
            _Pragma("unroll")                                                    \
            for (int k = 0; k < 8; ++k)                                          \
                XARR[k] = xh[(uint32_t)__float_as_int(RARR[k].x) + lane];        \
        }

#define FLUSH_H0()                                                               \
        {                                                                        \
            const int row = n - n0w;                                             \
            *(uint32_t*)&hb[row * 128 + (d0 ^ ((row & 7) << 4))] =               \
                pack2(fmaf(sc, (float)xnh.x, ax), fmaf(sc, (float)xnh.y, ay));   \
        }

#define STEP(K, MK)                                                              \
        {                                                                        \
            const int ek = e + K;                                                \
            if (ek < eend) {                                                     \
                while (ek >= nstop) {                                            \
                    FLUSH_H0();                                                  \
                    ax = 0.f; ay = 0.f; ++n;                                     \
                    xnh = __builtin_bit_cast(h2, xh[((uint32_t)n << 6) + lane]); \
                    nstop = __shfl(gs, n - n0w + 1, 64);                         \
                }                                                                \
                h2 mh = __builtin_bit_cast(h2, MK);                              \
                ax += (float)mh.x; ay += (float)mh.y;                            \
            }                                                                    \
        }

        float4 rc[8];
        uint32_t xc[8];
        if (ebase < eend) LOAD_BATCH(ebase, rc, xc);

        for (int e = ebase; e < eend; e += 8) {
            float4 rn[8];
            uint32_t xvn[8];
            const int en = e + 8;
            if (en < eend) {
                LOAD_BATCH(en, rn, xvn);          // next batch in flight now
            } else {
#pragma unroll
                for (int k = 0; k < 8; ++k) { rn[k] = rc[k]; xvn[k] = xc[k]; }
            }
            uint32_t m[8];
#pragma unroll
            for (int k = 0; k < 8; ++k)
                m[k] = edge_msg2(__float_as_uint(rc[k].y), __float_as_uint(rc[k].z),
                                 __float_as_uint(rc[k].w), xc[k], bbu,
                                 w0u, w1u, w2u, w3u, w4u, w5u);
            STEP(0, m[0])
            STEP(1, m[1])
            STEP(2, m[2])
            STEP(3, m[3])
            STEP(4, m[4])
            STEP(5, m[5])
            STEP(6, m[6])
            STEP(7, m[7])
#pragma unroll
            for (int k = 0; k < 8; ++k) { rc[k] = rn[k]; xc[k] = xvn[k]; }
        }
#undef STEP
#undef LOAD_BATCH

        // flush remaining (and empty/edge-less) nodes
        while (n < n1w) {
            FLUSH_H0();
            ax = 0.f; ay = 0.f; ++n;
            if (n < n1w) xnh = __builtin_bit_cast(h2, xh[((uint32_t)n << 6) + lane]);
        }
#undef FLUSH_H0
    }

    // ================= node phase =================
    const int l  = lane;
    const int lm = l & 15;
    const int lg = l >> 4;
    const int r0 = n0w;

    // A1 fragments from the wave's h0 LDS tile (XOR swizzle)
    half8 a1[4];
    {
        const int sw = (lm & 7) << 4;
        const _Float16* rowp = hb + lm * 128;
#pragma unroll
        for (int kt = 0; kt < 4; ++kt) {
            const int kb = kt * 32 + lg * 8;
            a1[kt] = *(const half8*)(rowp + (kb ^ sw));
        }
    }

    f32x4 acc[8];
#pragma unroll
    for (int nt = 0; nt < 8; ++nt) { acc[nt][0]=0.f; acc[nt][1]=0.f; acc[nt][2]=0.f; acc[nt][3]=0.f; }
#pragma unroll
    for (int kt = 0; kt < 4; ++kt) {
#pragma unroll
        for (int nt = 0; nt < 8; ++nt) {
            half8 bh = *(const half8*)(w1h + ((size_t)((kt * 8 + nt) * 64 + l)) * 8);
            acc[nt] = __builtin_amdgcn_mfma_f32_16x16x32_f16(a1[kt], bh, acc[nt], 0, 0, 0);
        }
    }

    // h1 overlaid on the same per-wave LDS tile (all a1 reads precede, in-order)
#pragma unroll
    for (int nt = 0; nt < 8; ++nt) {
        const int col = nt * 16 + lm;
        const float bias = b1[col];
#pragma unroll
        for (int q = 0; q < 4; ++q) {
            const int row = lg * 4 + q;
            float v1 = fmaxf(acc[nt][q] + bias, 0.f);
            hb[row * 128 + (col ^ ((row & 7) << 4))] = (_Float16)v1;
        }
    }

    half8 a2[4];
    {
        const int sw = (lm & 7) << 4;
        const _Float16* rowp = hb + lm * 128;
#pragma unroll
        for (int kt = 0; kt < 4; ++kt) {
            const int kb = kt * 32 + lg * 8;
            a2[kt] = *(const half8*)(rowp + (kb ^ sw));
        }
    }

    f32x4 acc2[8];
#pragma unroll
    for (int nt = 0; nt < 8; ++nt) { acc2[nt][0]=0.f; acc2[nt][1]=0.f; acc2[nt][2]=0.f; acc2[nt][3]=0.f; }
#pragma unroll
    for (int kt = 0; kt < 4; ++kt) {
#pragma unroll
        for (int nt = 0; nt < 8; ++nt) {
            half8 bh = *(const half8*)(w2h + ((size_t)((kt * 8 + nt) * 64 + l)) * 8);
            acc2[nt] = __builtin_amdgcn_mfma_f32_16x16x32_f16(a2[kt], bh, acc2[nt], 0, 0, 0);
        }
    }

    // LN stats from acc2+bias (no vv[] buffer — recompute at writeout)
    float sums[4] = {0,0,0,0}, sqs[4] = {0,0,0,0};
#pragma unroll
    for (int nt = 0; nt < 8; ++nt) {
        const float bias = b2[nt * 16 + lm];
#pragma unroll
        for (int q = 0; q < 4; ++q) {
            float v2 = acc2[nt][q] + bias;
            sums[q] += v2;
            sqs[q]  += v2 * v2;
        }
    }
#pragma unroll
    for (int m = 1; m < 16; m <<= 1) {
#pragma unroll
        for (int q = 0; q < 4; ++q) {
            sums[q] += __shfl_xor(sums[q], m, 64);
            sqs[q]  += __shfl_xor(sqs[q],  m, 64);
        }
    }

    float gam[8], bet[8], b2r[8];
#pragma unroll
    for (int nt = 0; nt < 8; ++nt) {
        gam[nt] = gamma[nt * 16 + lm];
        bet[nt] = beta[nt * 16 + lm];
        b2r[nt] = b2[nt * 16 + lm];
    }
#pragma unroll
    for (int q = 0; q < 4; ++q) {
        const int grow = r0 + lg * 4 + q;
        if (grow < NN) {
            const float mu  = sums[q] * (1.f / 128.f);
            const float var = sqs[q] * (1.f / 128.f) - mu * mu;
            const float rs  = rsqrtf(var + 1e-5f);
#pragma unroll
            for (int nt = 0; nt < 8; ++nt) {
                float v2 = acc2[nt][q] + b2r[nt];
                out[(size_t)grow * DD + nt * 16 + lm] =
                    fmaxf((v2 - mu) * rs * gam[nt] + bet[nt], 0.f);
            }
        }
    }
}

// ---------------------------------------------------------------------------
// Tier-B aggregation (no xh): 64 lanes/node, f32 x loads, writes h0h.
// (rec.x holds src*64; x row offset = src*64*2.)
// ---------------------------------------------------------------------------
#define NWAVE 8192
__global__ __launch_bounds__(256)
void agg_pk(const float* __restrict__ x, const float* __restrict__ rec,
            const float* __restrict__ We, const float* __restrict__ be,
            const int* __restrict__ start, const int* __restrict__ boff,
            const int* __restrict__ counts, const float* __restrict__ epsp,
            uint32_t* __restrict__ h0h)
{
    const int w = blockIdx.x * 4 + (threadIdx.x >> 6);
    const int lane = threadIdx.x & 63;
    const int d0 = lane * 2;
    const h2 w0h = cvt22(*(const float2*)(We + 0 * DD + d0));
    const h2 w1h = cvt22(*(const float2*)(We + 1 * DD + d0));
    const h2 w2h = cvt22(*(const float2*)(We + 2 * DD + d0));
    const h2 w3h = cvt22(*(const float2*)(We + 3 * DD + d0));
    const h2 w4h = cvt22(*(const float2*)(We + 4 * DD + d0));
    const h2 w5h = cvt22(*(const float2*)(We + 5 * DD + d0));
    const h2 bbh = cvt22(*(const float2*)(be + d0));
    h2 zero2; zero2.x = (_Float16)0.f; zero2.y = (_Float16)0.f;
    const float sc = 1.0f + epsp[0];
    const int n0 = (int)(((long long)w * NN) >> 13);
    const int n1 = (int)(((long long)(w + 1) * NN) >> 13);

    for (int n = n0; n < n1; ++n) {
        const int begin = start[n] + boff[n >> 10];
        const int cnt = counts[n];
        const float4* rp = (const float4*)rec + begin;
        float ax = 0.f, ay = 0.f;
        for (int i = 0; i < cnt; ++i) {
            float4 r = rp[i];
            int s64 = __float_as_int(r.x);
            h2 c01 = __builtin_bit_cast(h2, r.y);
            h2 c23 = __builtin_bit_cast(h2, r.z);
            h2 c45 = __builtin_bit_cast(h2, r.w);
            h2 emb = bbh;
            emb = bc_lo(c01) * w0h + emb;
            emb = bc_hi(c01) * w1h + emb;
            emb = bc_lo(c23) * w2h + emb;
            emb = bc_hi(c23) * w3h + emb;
            emb = bc_lo(c45) * w4h + emb;
            emb = bc_hi(c45) * w5h + emb;
            h2 m = emb + cvt22(*(const float2*)(x + (size_t)s64 * 2 + d0));
            m = __builtin_elementwise_max(m, zero2);
            ax += (float)m.x;
            ay += (float)m.y;
        }
        float2 xn = *(const float2*)(x + (size_t)n * DD + d0);
        h0h[(size_t)n * 64 + lane] = pack2(fmaf(sc, xn.x, ax), fmaf(sc, xn.y, ay));
    }
}

// ---------------------------------------------------------------------------
// Tier-B node kernel (h0 packed f16 in global).
// ---------------------------------------------------------------------------
__global__ __launch_bounds__(256)
void node_f16(const uint32_t* __restrict__ h0h,
              const _Float16* __restrict__ w1h, const _Float16* __restrict__ w2h,
              const float* __restrict__ b1, const float* __restrict__ b2,
              const float* __restrict__ gamma, const float* __restrict__ beta,
              float* __restrict__ out)
{
    __shared__ _Float16 h1buf[4][16 * 128];
    const int wv = threadIdx.x >> 6;
    const int l  = threadIdx.x & 63;
    const int lm = l & 15;
    const int lg = l >> 4;
    const int rbase = blockIdx.x * 128 + wv * 32;

    float gam[8], bet[8];
#pragma unroll
    for (int nt = 0; nt < 8; ++nt) {
        gam[nt] = gamma[nt * 16 + lm];
        bet[nt] = beta[nt * 16 + lm];
    }

    for (int t = 0; t < 2; ++t) {
        const int r0 = rbase + t * 16;
        int arow = r0 + lm;
        if (arow >= NN) arow = NN - 1;

        half8 a1[4];
#pragma unroll
        for (int kt = 0; kt < 4; ++kt) {
            const int kb = kt * 32 + lg * 8;
            a1[kt] = *(const half8*)((const _Float16*)h0h + (size_t)arow * DD + kb);
        }

        f32x4 acc[8];
#pragma unroll
        for (int nt = 0; nt < 8; ++nt) { acc[nt][0]=0.f; acc[nt][1]=0.f; acc[nt][2]=0.f; acc[nt][3]=0.f; }
#pragma unroll
        for (int kt = 0; kt < 4; ++kt) {
#pragma unroll
            for (int nt = 0; nt < 8; ++nt) {
                half8 bh = *(const half8*)(w1h + ((size_t)((kt * 8 + nt) * 64 + l)) * 8);
                acc[nt] = __builtin_amdgcn_mfma_f32_16x16x32_f16(a1[kt], bh, acc[nt], 0, 0, 0);
            }
        }

        _Float16* hb = h1buf[wv];
#pragma unroll
        for (int nt = 0; nt < 8; ++nt) {
            const int col = nt * 16 + lm;
            const float bias = b1[col];
#pragma unroll
            for (int q = 0; q < 4; ++q) {
                const int row = lg * 4 + q;
                float v1 = fmaxf(acc[nt][q] + bias, 0.f);
                hb[row * 128 + (col ^ ((row & 7) << 4))] = (_Float16)v1;
            }
        }

        half8 a2[4];
        {
            const int sw = (lm & 7) << 4;
            const _Float16* rowp = hb + lm * 128;
#pragma unroll
            for (int kt = 0; kt < 4; ++kt) {
                const int kb = kt * 32 + lg * 8;
                a2[kt] = *(const half8*)(rowp + (kb ^ sw));
            }
        }

        f32x4 acc2[8];
#pragma unroll
        for (int nt = 0; nt < 8; ++nt) { acc2[nt][0]=0.f; acc2[nt][1]=0.f; acc2[nt][2]=0.f; acc2[nt][3]=0.f; }
#pragma unroll
        for (int kt = 0; kt < 4; ++kt) {
#pragma unroll
            for (int nt = 0; nt < 8; ++nt) {
                half8 bh = *(const half8*)(w2h + ((size_t)((kt * 8 + nt) * 64 + l)) * 8);
                acc2[nt] = __builtin_amdgcn_mfma_f32_16x16x32_f16(a2[kt], bh, acc2[nt], 0, 0, 0);
            }
        }

        float vv[8][4];
        float sums[4] = {0,0,0,0}, sqs[4] = {0,0,0,0};
#pragma unroll
        for (int nt = 0; nt < 8; ++nt) {
            const int col = nt * 16 + lm;
            const float bias = b2[col];
#pragma unroll
            for (int q = 0; q < 4; ++q) {
                float v2 = acc2[nt][q] + bias;
                vv[nt][q] = v2;
                sums[q] += v2;
                sqs[q]  += v2 * v2;
            }
        }
#pragma unroll
        for (int m = 1; m < 16; m <<= 1) {
#pragma unroll
            for (int q = 0; q < 4; ++q) {
                sums[q] += __shfl_xor(sums[q], m, 64);
                sqs[q]  += __shfl_xor(sqs[q],  m, 64);
            }
        }
#pragma unroll
        for (int q = 0; q < 4; ++q) {
            const int grow = r0 + lg * 4 + q;
            if (grow < NN) {
                const float mu  = sums[q] * (1.f / 128.f);
                const float var = sqs[q] * (1.f / 128.f) - mu * mu;
                const float rs  = rsqrtf(var + 1e-5f);
#pragma unroll
                for (int nt = 0; nt < 8; ++nt) {
                    out[(size_t)grow * DD + nt * 16 + lm] =
                        fmaxf((vv[nt][q] - mu) * rs * gam[nt] + bet[nt], 0.f);
                }
            }
        }
    }
}

// ---------------------------------------------------------------------------
// Tier-C fallback kernels.
// ---------------------------------------------------------------------------
__global__ __launch_bounds__(256)
void prep_w(const float* __restrict__ W1, const float* __restrict__ W2,
            _Float16* __restrict__ w1h, _Float16* __restrict__ w2h)
{
    int t = blockIdx.x * 256 + threadIdx.x;
    if (t >= 2 * DD * DD) return;
    int which = t >> 14;
    int idx = t & (DD * DD - 1);
    int k = idx >> 7, d = idx & 127;
    float wv = (which ? W2 : W1)[k * DD + d];
    int kt = k >> 5, kr = k & 31;
    int grp = kr >> 3, j = kr & 7;
    int nt = d >> 4, cc = d & 15;
    int off = ((kt * 8 + nt) * 64 + grp * 16 + cc) * 8 + j;
    (which ? w2h : w1h)[off] = (_Float16)wv;
}

__global__ __launch_bounds__(256)
void edge_kernel(const float* __restrict__ x, const int* __restrict__ ei,
                 const float* __restrict__ ea, const float* __restrict__ We,
                 const float* __restrict__ be, float* agg)
{
    int tid = blockIdx.x * 256 + threadIdx.x;
    int d0 = (tid & 31) * 4;
    float4 w0 = *(const float4*)(We + 0 * DD + d0);
    float4 w1 = *(const float4*)(We + 1 * DD + d0);
    float4 w2 = *(const float4*)(We + 2 * DD + d0);
    float4 w3 = *(const float4*)(We + 3 * DD + d0);
    float4 w4 = *(const float4*)(We + 4 * DD + d0);
    float4 w5 = *(const float4*)(We + 5 * DD + d0);
    float4 bb = *(const float4*)(be + d0);
    int estride = (gridDim.x * 256) >> 5;
    for (int e = tid >> 5; e < EE; e += estride) {
        int src = ei[e];
        int dst = ei[EE + e];
        const float2* eap = (const float2*)(ea + e * 6);
        float2 e01 = eap[0];
        float2 e23 = eap[1];
        float2 e45 = eap[2];
        float4 xj = *(const float4*)(x + (size_t)src * DD + d0);
        float mx = xj.x + bb.x + e01.x*w0.x + e01.y*w1.x + e23.x*w2.x + e23.y*w3.x + e45.x*w4.x + e45.y*w5.x;
        float my = xj.y + bb.y + e01.x*w0.y + e01.y*w1.y + e23.x*w2.y + e23.y*w3.y + e45.x*w4.y + e45.y*w5.y;
        float mz = xj.z + bb.z + e01.x*w0.z + e01.y*w1.z + e23.x*w2.z + e23.y*w3.z + e45.x*w4.z + e45.y*w5.z;
        float mw = xj.w + bb.w + e01.x*w0.w + e01.y*w1.w + e23.x*w2.w + e23.y*w3.w + e45.x*w4.w + e45.y*w5.w;
        float* ap = agg + (size_t)dst * DD + d0;
        atomicAdd(ap + 0, fmaxf(mx, 0.f));
        atomicAdd(ap + 1, fmaxf(my, 0.f));
        atomicAdd(ap + 2, fmaxf(mz, 0.f));
        atomicAdd(ap + 3, fmaxf(mw, 0.f));
    }
}

__global__ __launch_bounds__(256)
void node2c(const float* __restrict__ aggp, const float* __restrict__ xp,
            const _Float16* __restrict__ w1h, const _Float16* __restrict__ w2h,
            const float* __restrict__ b1, const float* __restrict__ b2,
            const float* __restrict__ gamma, const float* __restrict__ beta,
            const float* __restrict__ epsp, float* __restrict__ out)
{
    __shared__ _Float16 h1buf[4][16 * 128];
    const int wv = threadIdx.x >> 6;
    const int l  = threadIdx.x & 63;
    const int lm = l & 15;
    const int lg = l >> 4;
    const int rbase = blockIdx.x * 128 + wv * 32;

    float gam[8], bet[8];
#pragma unroll
    for (int nt = 0; nt < 8; ++nt) {
        gam[nt] = gamma[nt * 16 + lm];
        bet[nt] = beta[nt * 16 + lm];
    }

    for (int t = 0; t < 2; ++t) {
        const int r0 = rbase + t * 16;
        int arow = r0 + lm;
        if (arow >= NN) arow = NN - 1;

        half8 a1[4];
#pragma unroll
        for (int kt = 0; kt < 4; ++kt) {
            const int kb = kt * 32 + lg * 8;
            const float4* hp = (const float4*)(aggp + (size_t)arow * DD + kb);
            float4 p0 = hp[0], p1 = hp[1];
            const float scale = 1.0f + epsp[0];
            const float4* xr = (const float4*)(xp + (size_t)arow * DD + kb);
            float4 x0 = xr[0], x1 = xr[1];
            float v[8] = { x0.x*scale+p0.x, x0.y*scale+p0.y, x0.z*scale+p0.z, x0.w*scale+p0.w,
                           x1.x*scale+p1.x, x1.y*scale+p1.y, x1.z*scale+p1.z, x1.w*scale+p1.w };
#pragma unroll
            for (int j = 0; j < 8; ++j) a1[kt][j] = (_Float16)v[j];
        }

        f32x4 acc[8];
#pragma unroll
        for (int nt = 0; nt < 8; ++nt) { acc[nt][0]=0.f; acc[nt][1]=0.f; acc[nt][2]=0.f; acc[nt][3]=0.f; }
#pragma unroll
        for (int kt = 0; kt < 4; ++kt) {
#pragma unroll
            for (int nt = 0; nt < 8; ++nt) {
                half8 bh = *(const half8*)(w1h + ((size_t)((kt * 8 + nt) * 64 + l)) * 8);
                acc[nt] = __builtin_amdgcn_mfma_f32_16x16x32_f16(a1[kt], bh, acc[nt], 0, 0, 0);
            }
        }

        _Float16* hb = h1buf[wv];
#pragma unroll
        for (int nt = 0; nt < 8; ++nt) {
            const int col = nt * 16 + lm;
            const float bias = b1[col];
#pragma unroll
            for (int q = 0; q < 4; ++q) {
                const int row = lg * 4 + q;
                float v1 = fmaxf(acc[nt][q] + bias, 0.f);
                hb[row * 128 + (col ^ ((row & 7) << 4))] = (_Float16)v1;
            }
        }

        half8 a2[4];
        {
            const int sw = (lm & 7) << 4;
            const _Float16* rowp = hb + lm * 128;
#pragma unroll
            for (int kt = 0; kt < 4; ++kt) {
                const int kb = kt * 32 + lg * 8;
                a2[kt] = *(const half8*)(rowp + (kb ^ sw));
            }
        }

        f32x4 acc2[8];
#pragma unroll
        for (int nt = 0; nt < 8; ++nt) { acc2[nt][0]=0.f; acc2[nt][1]=0.f; acc2[nt][2]=0.f; acc2[nt][3]=0.f; }
#pragma unroll
        for (int kt = 0; kt < 4; ++kt) {
#pragma unroll
            for (int nt = 0; nt < 8; ++nt) {
                half8 bh = *(const half8*)(w2h + ((size_t)((kt * 8 + nt) * 64 + l)) * 8);
                acc2[nt] = __builtin_amdgcn_mfma_f32_16x16x32_f16(a2[kt], bh, acc2[nt], 0, 0, 0);
            }
        }

        float vv[8][4];
        float sums[4] = {0,0,0,0}, sqs[4] = {0,0,0,0};
#pragma unroll
        for (int nt = 0; nt < 8; ++nt) {
            const int col = nt * 16 + lm;
            const float bias = b2[col];
#pragma unroll
            for (int q = 0; q < 4; ++q) {
                float v2 = acc2[nt][q] + bias;
                vv[nt][q] = v2;
                sums[q] += v2;
                sqs[q]  += v2 * v2;
            }
        }
#pragma unroll
        for (int m = 1; m < 16; m <<= 1) {
#pragma unroll
            for (int q = 0; q < 4; ++q) {
                sums[q] += __shfl_xor(sums[q], m, 64);
                sqs[q]  += __shfl_xor(sqs[q],  m, 64);
            }
        }
#pragma unroll
        for (int q = 0; q < 4; ++q) {
            const int grow = r0 + lg * 4 + q;
            if (grow < NN) {
                const float mu  = sums[q] * (1.f / 128.f);
                const float var = sqs[q] * (1.f / 128.f) - mu * mu;
                const float rs  = rsqrtf(var + 1e-5f);
#pragma unroll
                for (int nt = 0; nt < 8; ++nt) {
                    out[(size_t)grow * DD + nt * 16 + lm] =
                        fmaxf((vv[nt][q] - mu) * rs * gam[nt] + bet[nt], 0.f);
                }
            }
        }
    }
}

extern "C" void kernel_launch(void* const* d_in, const int* in_sizes, int n_in,
                              void* d_out, int out_size, void* d_ws, size_t ws_size,
                              hipStream_t stream) {
    (void)in_sizes; (void)n_in; (void)out_size;
    const float* x     = (const float*)d_in[0];
    const int*   ei    = (const int*)d_in[1];
    const float* ea    = (const float*)d_in[2];
    const float* We    = (const float*)d_in[4];
    const float* be    = (const float*)d_in[5];
    const float* epsp  = (const float*)d_in[6];
    const float* W1    = (const float*)d_in[7];
    const float* b1    = (const float*)d_in[8];
    const float* W2    = (const float*)d_in[9];
    const float* b2    = (const float*)d_in[10];
    const float* gamma = (const float*)d_in[11];
    const float* beta  = (const float*)d_in[12];
    float* out = (float*)d_out;

    // ---- workspace layout (16B-aligned)
    char* ws = (char*)d_ws;
    _Float16* w1h = (_Float16*)ws;
    _Float16* w2h = w1h + DD * DD;
    size_t off = 2 * (size_t)DD * DD * sizeof(_Float16);      // 65536
    int* counts = (int*)(ws + off);   off += (size_t)NN * 4;
    int* cursor = (int*)(ws + off);   off += (size_t)NN * 4;
    int* start  = (int*)(ws + off);   off += (size_t)NN * 4;
    int* bsum   = (int*)(ws + off);   off += 512;
    int* boff   = (int*)(ws + off);   off += 512;
    float* rec  = (float*)(ws + off); off += (size_t)EE * 16;
    uint32_t* h0h = (uint32_t*)(ws + off); off += (size_t)NN * DD * 2;
    const size_t need_h0 = off;                                // ~36.9 MB
    uint32_t* xh  = (uint32_t*)(ws + off); off += (size_t)NN * DD * 2;
    const size_t need_xh = off;                                // ~62.5 MB

    const int node_blocks = (NN + 127) / 128;
    const int fused_blocks = (NN + 63) / 64;
    const int NBLK = (NN + 1023) / 1024;

    if (ws_size >= need_h0) {
        const bool conv = (ws_size >= need_xh);
        hipMemsetAsync(counts, 0, 2 * (size_t)NN * 4, stream);  // counts + cursor
        if (conv) {
            setup_kernel<true><<<NB_HIST + NB_CONV + 128, 256, 0, stream>>>(
                ei, x, W1, W2, counts, xh, w1h, w2h);
        } else {
            setup_kernel<false><<<NB_HIST + 128, 256, 0, stream>>>(
                ei, x, W1, W2, counts, xh, w1h, w2h);
        }
        scan_blocks<<<NBLK, 256, 0, stream>>>(counts, start, bsum);
        scan_top<<<1, 128, 0, stream>>>(bsum, boff);
        scatter_rec<<<(EE + 255) / 256, 256, 0, stream>>>(ei, ea, start, boff, cursor, rec);
        if (conv) {
            fused_an<<<fused_blocks, 256, 0, stream>>>(xh, (const float4*)rec, We, be,
                                                       start, boff, epsp, w1h, w2h,
                                                       b1, b2, gamma, beta, out);
        } else {
            agg_pk<<<NWAVE / 4, 256, 0, stream>>>(x, rec, We, be, start, boff,
                                                  counts, epsp, h0h);
            node_f16<<<node_blocks, 256, 0, stream>>>(h0h, w1h, w2h, b1, b2, gamma, beta, out);
        }
    } else {
        // Tier C: atomic scatter into d_out, node computes h0 in-kernel.
        hipMemsetAsync(d_out, 0, (size_t)NN * DD * sizeof(float), stream);
        prep_w<<<(2 * DD * DD + 255) / 256, 256, 0, stream>>>(W1, W2, w1h, w2h);
        edge_kernel<<<2048, 256, 0, stream>>>(x, ei, ea, We, be, out);
        node2c<<<node_blocks, 256, 0, stream>>>(out, x, w1h, w2h, b1, b2,
                                                gamma, beta, epsp, out);
    }
}